// Round 5
// baseline (290.016 us; speedup 1.0000x reference)
//
#include <hip/hip_runtime.h>
#include <hip/hip_bf16.h>
#include <math.h>

// Problem constants (fixed by setup_inputs)
#define Bq 8
#define Nq 2048
#define Pq 64
#define Dq 128
#define Kq 16
#define BNq (Bq * Nq)   // 16384 points total

typedef unsigned short u16;
typedef __bf16 bf16x8v __attribute__((ext_vector_type(8)));
typedef float f32x4v __attribute__((ext_vector_type(4)));

__device__ __forceinline__ u16 f2b(float f) {
    return __builtin_bit_cast(u16, (__bf16)f);      // RNE
}

// Wt element offsets (all matrices stored transposed bf16: Wt[n][k] = W[k][n])
#define OFF_DEL2 0
#define OFF_GAM1 16384
#define OFF_GAM2 32768
#define OFF_FC1  49152
#define OFF_PHI  57344
#define OFF_PSI  73728
#define OFF_ALF  90112
#define OFF_DPT1 106496
#define OFF_DPT2 122880
#define WT_TOTAL 139264

// ---------------------------------------------------------------------------
// Kernel 0: transpose+convert all 9 matmul weights -> bf16 Wt[n][K] linear.
// ---------------------------------------------------------------------------
__global__ __launch_bounds__(256) void prep_kernel(
    const float* __restrict__ Wdel2, const float* __restrict__ Wgam1,
    const float* __restrict__ Wgam2, const float* __restrict__ Wfc1,
    const float* __restrict__ Wphi, const float* __restrict__ Wpsi,
    const float* __restrict__ Walpha, const float* __restrict__ Wdpt1,
    const float* __restrict__ Wdpt2, u16* __restrict__ Wt) {
    int idx = blockIdx.x * 256 + threadIdx.x;       // 0..139263
    const float* W;
    int n, k;
    if (idx < OFF_FC1) {
        int m = idx >> 14, r = idx & 16383;
        W = (m == 0) ? Wdel2 : (m == 1) ? Wgam1 : Wgam2;
        n = r >> 7; k = r & 127;
    } else if (idx < OFF_PHI) {
        int r = idx - OFF_FC1;
        W = Wfc1; n = r >> 6; k = r & 63;
    } else {
        int r = idx - OFF_PHI;
        int m = r >> 14; r &= 16383;
        W = (m == 0) ? Wphi : (m == 1) ? Wpsi : (m == 2) ? Walpha : (m == 3) ? Wdpt1 : Wdpt2;
        n = r >> 7; k = r & 127;
    }
    Wt[idx] = f2b(W[k * 128 + n]);
}

// ---------------------------------------------------------------------------
// Kernel 1 (v3): exact kNN. 512 blocks x 512 threads.
// Block = 32 queries x 16 candidate-chunks of 128. Per-thread top-16
// (strict-< insertion), then stable lex (d,idx) merge: 16->8 pair merges
// (256 threads) then 8-way final merge (32 threads).
// ---------------------------------------------------------------------------
__global__ __launch_bounds__(512) void knn_kernel(const float* __restrict__ x,
                                                  int* __restrict__ knn) {
    __shared__ float4 sx[Nq];                       // 32 KB
    __shared__ float sLd[32][16][17];               // 34 KB
    __shared__ u16   sLi[32][16][17];               // 17 KB
    const int b = blockIdx.x >> 6;
    const int q0 = (blockIdx.x & 63) * 32;
    const float* xb = x + b * Nq * 3;
    for (int j = threadIdx.x; j < Nq; j += 512) {
        float x0 = xb[j * 3 + 0], x1 = xb[j * 3 + 1], x2 = xb[j * 3 + 2];
        // replicate jnp.sum(x*x): no fma contraction
        float n2 = __fadd_rn(__fadd_rn(__fmul_rn(x0, x0), __fmul_rn(x1, x1)),
                             __fmul_rn(x2, x2));
        sx[j] = make_float4(x0, x1, x2, n2);
    }
    __syncthreads();
    const int q = threadIdx.x & 31;
    const int sub = threadIdx.x >> 5;               // 0..15
    const float4 qv = sx[q0 + q];
    float bd[Kq];
    int bj[Kq];
#pragma unroll
    for (int s = 0; s < Kq; ++s) { bd[s] = INFINITY; bj[s] = 0x7fff; }
    const int j0 = sub * 128;
    for (int i = 0; i < 128; ++i) {
        const int j = j0 + i;
        float4 p = sx[j];
        float dot = __fadd_rn(__fadd_rn(__fmul_rn(qv.x, p.x), __fmul_rn(qv.y, p.y)),
                              __fmul_rn(qv.z, p.z));
        float d = __fsub_rn(__fadd_rn(qv.w, p.w), __fmul_rn(2.0f, dot));
        if (d < bd[Kq - 1]) {                       // strict <: stable
            bd[Kq - 1] = d; bj[Kq - 1] = j;
#pragma unroll
            for (int s = Kq - 1; s >= 1; --s) {
                if (bd[s] < bd[s - 1]) {
                    float td = bd[s]; bd[s] = bd[s - 1]; bd[s - 1] = td;
                    int tj = bj[s]; bj[s] = bj[s - 1]; bj[s - 1] = tj;
                }
            }
        }
    }
#pragma unroll
    for (int s = 0; s < Kq; ++s) { sLd[q][sub][s] = bd[s]; sLi[q][sub][s] = (u16)bj[s]; }
    __syncthreads();
    // ---- step 1: pair merges (2 lists -> 16 best), 256 threads ----
    if (threadIdx.x < 256) {
        const int mq = threadIdx.x & 31;
        const int s2 = threadIdx.x >> 5;            // 0..7 -> lists 2*s2, 2*s2+1
        float md[Kq]; int mi[Kq];
        int pa = 0, pb = 0;
#pragma unroll
        for (int i = 0; i < Kq; ++i) {
            float da = sLd[mq][2 * s2][pa], db = sLd[mq][2 * s2 + 1][pb];
            int ia = sLi[mq][2 * s2][pa], ib = sLi[mq][2 * s2 + 1][pb];
            bool ta = (da < db) || (da == db && ia < ib);
            md[i] = ta ? da : db; mi[i] = ta ? ia : ib;
            if (ta) ++pa; else ++pb;
        }
#pragma unroll
        for (int i = 0; i < Kq; ++i) { sLd[mq][2 * s2][i] = md[i]; sLi[mq][2 * s2][i] = (u16)mi[i]; }
    }
    __syncthreads();
    // ---- step 2: stable 8-way merge (one thread per query) ----
    if (threadIdx.x < 32) {
        const int mq = threadIdx.x;
        int pos[8]; float hd[8]; int hi[8];
#pragma unroll
        for (int s = 0; s < 8; ++s) {
            pos[s] = 1; hd[s] = sLd[mq][2 * s][0]; hi[s] = sLi[mq][2 * s][0];
        }
        int* o = knn + (b * Nq + q0 + mq) * Kq;
#pragma unroll
        for (int oi = 0; oi < Kq; ++oi) {
            float bdv = hd[0]; int biv = hi[0]; int bs = 0;
#pragma unroll
            for (int s = 1; s < 8; ++s) {
                bool take = (hd[s] < bdv) || (hd[s] == bdv && hi[s] < biv);
                if (take) { bdv = hd[s]; biv = hi[s]; bs = s; }
            }
            o[oi] = biv;
#pragma unroll
            for (int s = 0; s < 8; ++s) {           // static-index update
                if (s == bs) {
                    int pp = pos[s] < Kq ? pos[s] : (Kq - 1);
                    bool ok = pos[s] < Kq;
                    hd[s] = ok ? sLd[mq][2 * s][pp] : INFINITY;
                    hi[s] = ok ? sLi[mq][2 * s][pp] : 0x7fffffff;
                    pos[s]++;
                }
            }
        }
    }
}

// ---------------------------------------------------------------------------
// Shared MFMA helpers (feat kernel). XOR swizzle byte ^= (row&7)<<4.
// ---------------------------------------------------------------------------
template <int BYTES, int ROWBYTES>
__device__ __forceinline__ void stageW(const u16* __restrict__ src,
                                       u16* __restrict__ sW, int t) {
#pragma unroll
    for (int c = 0; c < BYTES / 4096; ++c) {
        int lin = c * 4096 + t * 16;
        int n = lin / ROWBYTES;
        int o = lin % ROWBYTES;
        bf16x8v v = *(const bf16x8v*)((const char*)src + lin);
        *(bf16x8v*)((char*)sW + n * ROWBYTES + (o ^ ((n & 7) << 4))) = v;
    }
}

__device__ __forceinline__ void mfma_k128(const u16* __restrict__ sA,
                                          const u16* __restrict__ sW,
                                          int colbase, int lane,
                                          f32x4v (&acc)[4][2]) {
    const int kg = lane >> 4;
    const int l15 = lane & 15;
#pragma unroll
    for (int ks = 0; ks < 4; ++ks) {
        bf16x8v a[4], bfr[2];
#pragma unroll
        for (int m = 0; m < 4; ++m) {
            int row = m * 16 + l15;
            int o = (ks * 64 + kg * 16) ^ ((row & 7) << 4);
            a[m] = *(const bf16x8v*)((const char*)sA + row * 256 + o);
        }
#pragma unroll
        for (int nt = 0; nt < 2; ++nt) {
            int n = colbase + nt * 16 + l15;
            int o = (ks * 64 + kg * 16) ^ ((n & 7) << 4);
            bfr[nt] = *(const bf16x8v*)((const char*)sW + n * 256 + o);
        }
#pragma unroll
        for (int m = 0; m < 4; ++m)
#pragma unroll
            for (int nt = 0; nt < 2; ++nt)
                acc[m][nt] = __builtin_amdgcn_mfma_f32_16x16x32_bf16(a[m], bfr[nt], acc[m][nt], 0, 0, 0);
    }
}

__device__ __forceinline__ void mfma_k64(const u16* __restrict__ sA,
                                         const u16* __restrict__ sW,
                                         int colbase, int lane,
                                         f32x4v (&acc)[4][2]) {
    const int kg = lane >> 4;
    const int l15 = lane & 15;
#pragma unroll
    for (int ks = 0; ks < 2; ++ks) {
        bf16x8v a[4], bfr[2];
#pragma unroll
        for (int m = 0; m < 4; ++m) {
            int row = m * 16 + l15;
            int o = (ks * 64 + kg * 16) ^ ((row & 7) << 4);
            a[m] = *(const bf16x8v*)((const char*)sA + row * 128 + o);
        }
#pragma unroll
        for (int nt = 0; nt < 2; ++nt) {
            int n = colbase + nt * 16 + l15;
            int o = (ks * 64 + kg * 16) ^ ((n & 7) << 4);
            bfr[nt] = *(const bf16x8v*)((const char*)sW + n * 128 + o);
        }
#pragma unroll
        for (int m = 0; m < 4; ++m)
#pragma unroll
            for (int nt = 0; nt < 2; ++nt)
                acc[m][nt] = __builtin_amdgcn_mfma_f32_16x16x32_bf16(a[m], bfr[nt], acc[m][nt], 0, 0, 0);
    }
}

// ---------------------------------------------------------------------------
// Kernel 2 (MFMA): per-point features, 64 points/block, 256 blocks x 4 waves.
// (unchanged from round 3)
// ---------------------------------------------------------------------------
__global__ __launch_bounds__(256, 2) void feat_kernel(
    const float* __restrict__ in_f, const u16* __restrict__ Wt,
    const float* __restrict__ bfc1, const float* __restrict__ bdpt1,
    const float* __restrict__ bdpt2,
    float* __restrict__ base, u16* __restrict__ psiB, u16* __restrict__ alphaB) {
    __shared__ __align__(16) u16 sIn[64 * 64];      // 8 KB
    __shared__ __align__(16) u16 sF[64 * 128];      // 16 KB
    __shared__ __align__(16) u16 sW[128 * 128];     // 32 KB
    const int t = threadIdx.x;
    const int lane = t & 63;
    const int w = t >> 6;
    const int kg = lane >> 4;
    const int l15 = lane & 15;
    const int p0 = blockIdx.x * 64;

    {
        const int r = t >> 2;
        const int c0 = (t & 3) * 16;
        const float* src = &in_f[(size_t)(p0 + r) * 64 + c0];
        float4 v0 = *(const float4*)(src + 0);
        float4 v1 = *(const float4*)(src + 4);
        float4 v2 = *(const float4*)(src + 8);
        float4 v3 = *(const float4*)(src + 12);
        bf16x8v lo, hi;
        lo[0] = (__bf16)v0.x; lo[1] = (__bf16)v0.y; lo[2] = (__bf16)v0.z; lo[3] = (__bf16)v0.w;
        lo[4] = (__bf16)v1.x; lo[5] = (__bf16)v1.y; lo[6] = (__bf16)v1.z; lo[7] = (__bf16)v1.w;
        hi[0] = (__bf16)v2.x; hi[1] = (__bf16)v2.y; hi[2] = (__bf16)v2.z; hi[3] = (__bf16)v2.w;
        hi[4] = (__bf16)v3.x; hi[5] = (__bf16)v3.y; hi[6] = (__bf16)v3.z; hi[7] = (__bf16)v3.w;
        const int swz = (r & 7) << 4;
        *(bf16x8v*)((char*)sIn + r * 128 + ((c0 * 2) ^ swz)) = lo;
        *(bf16x8v*)((char*)sIn + r * 128 + (((c0 + 8) * 2) ^ swz)) = hi;
    }

    f32x4v acc[4][2], accPhi[4][2];

    {
        float bv0 = bfc1[w * 32 + l15];
        float bv1 = bfc1[w * 32 + 16 + l15];
#pragma unroll
        for (int m = 0; m < 4; ++m) { acc[m][0] = f32x4v{bv0, bv0, bv0, bv0}; acc[m][1] = f32x4v{bv1, bv1, bv1, bv1}; }
    }
    stageW<16384, 128>(Wt + OFF_FC1, sW, t);
    __syncthreads();
    mfma_k64(sIn, sW, w * 32, lane, acc);

#pragma unroll
    for (int m = 0; m < 4; ++m)
#pragma unroll
        for (int nt = 0; nt < 2; ++nt)
#pragma unroll
            for (int rr = 0; rr < 4; ++rr) {
                int row = m * 16 + kg * 4 + rr;
                int col = w * 32 + nt * 16 + l15;
                *(__bf16*)((char*)sF + row * 256 + ((col * 2) ^ ((row & 7) << 4))) = (__bf16)acc[m][nt][rr];
            }

#pragma unroll
    for (int m = 0; m < 4; ++m) { accPhi[m][0] = f32x4v{0, 0, 0, 0}; accPhi[m][1] = f32x4v{0, 0, 0, 0}; }
    __syncthreads();
    stageW<32768, 256>(Wt + OFF_PHI, sW, t);
    __syncthreads();
    mfma_k128(sF, sW, w * 32, lane, accPhi);

#pragma unroll
    for (int m = 0; m < 4; ++m) { acc[m][0] = f32x4v{0, 0, 0, 0}; acc[m][1] = f32x4v{0, 0, 0, 0}; }
    __syncthreads();
    stageW<32768, 256>(Wt + OFF_PSI, sW, t);
    __syncthreads();
    mfma_k128(sF, sW, w * 32, lane, acc);
#pragma unroll
    for (int m = 0; m < 4; ++m)
#pragma unroll
        for (int nt = 0; nt < 2; ++nt)
#pragma unroll
            for (int rr = 0; rr < 4; ++rr) {
                int row = m * 16 + kg * 4 + rr;
                int col = w * 32 + nt * 16 + l15;
                psiB[(size_t)(p0 + row) * 128 + col] = f2b(acc[m][nt][rr]);
            }

#pragma unroll
    for (int m = 0; m < 4; ++m) { acc[m][0] = f32x4v{0, 0, 0, 0}; acc[m][1] = f32x4v{0, 0, 0, 0}; }
    __syncthreads();
    stageW<32768, 256>(Wt + OFF_ALF, sW, t);
    __syncthreads();
    mfma_k128(sF, sW, w * 32, lane, acc);
#pragma unroll
    for (int m = 0; m < 4; ++m)
#pragma unroll
        for (int nt = 0; nt < 2; ++nt)
#pragma unroll
            for (int rr = 0; rr < 4; ++rr) {
                int row = m * 16 + kg * 4 + rr;
                int col = w * 32 + nt * 16 + l15;
                alphaB[(size_t)(p0 + row) * 128 + col] = f2b(acc[m][nt][rr]);
            }

    {
        float bv0 = bdpt1[w * 32 + l15];
        float bv1 = bdpt1[w * 32 + 16 + l15];
#pragma unroll
        for (int m = 0; m < 4; ++m) { acc[m][0] = f32x4v{bv0, bv0, bv0, bv0}; acc[m][1] = f32x4v{bv1, bv1, bv1, bv1}; }
    }
    __syncthreads();
    stageW<32768, 256>(Wt + OFF_DPT1, sW, t);
    __syncthreads();
    mfma_k128(sF, sW, w * 32, lane, acc);
    __syncthreads();
#pragma unroll
    for (int m = 0; m < 4; ++m)
#pragma unroll
        for (int nt = 0; nt < 2; ++nt)
#pragma unroll
            for (int rr = 0; rr < 4; ++rr) {
                int row = m * 16 + kg * 4 + rr;
                int col = w * 32 + nt * 16 + l15;
                *(__bf16*)((char*)sF + row * 256 + ((col * 2) ^ ((row & 7) << 4))) =
                    (__bf16)fmaxf(acc[m][nt][rr], 0.f);
            }

    {
        float bv0 = bdpt2[w * 32 + l15];
        float bv1 = bdpt2[w * 32 + 16 + l15];
#pragma unroll
        for (int m = 0; m < 4; ++m) { acc[m][0] = f32x4v{bv0, bv0, bv0, bv0}; acc[m][1] = f32x4v{bv1, bv1, bv1, bv1}; }
    }
    __syncthreads();
    stageW<32768, 256>(Wt + OFF_DPT2, sW, t);
    __syncthreads();
    mfma_k128(sF, sW, w * 32, lane, acc);
#pragma unroll
    for (int m = 0; m < 4; ++m)
#pragma unroll
        for (int nt = 0; nt < 2; ++nt)
#pragma unroll
            for (int rr = 0; rr < 4; ++rr) {
                int row = m * 16 + kg * 4 + rr;
                int col = w * 32 + nt * 16 + l15;
                base[(size_t)(p0 + row) * 128 + col] = acc[m][nt][rr] + accPhi[m][nt][rr];
            }
}

// ---------------------------------------------------------------------------
// Kernel 3 (persistent MFMA): 256 blocks (1/CU) x 512 threads (8 waves).
// Stage all 3 stage-weights ONCE (96 KB LDS), then loop 16 chunks x 4 points.
// N split across 8 waves (16 cols each, acc[4] per wave). 7 barriers/chunk.
// ---------------------------------------------------------------------------
__device__ __forceinline__ void mfma_n1(const u16* __restrict__ sA,
                                        const u16* __restrict__ sW,
                                        int colW, int kg, int l15,
                                        f32x4v (&acc)[4]) {
#pragma unroll
    for (int ks = 0; ks < 4; ++ks) {
        bf16x8v a[4], bb;
#pragma unroll
        for (int m = 0; m < 4; ++m) {
            int row = m * 16 + l15;
            int o = (ks * 64 + kg * 16) ^ ((row & 7) << 4);
            a[m] = *(const bf16x8v*)((const char*)sA + row * 256 + o);
        }
        {
            int o = (ks * 64 + kg * 16) ^ ((colW & 7) << 4);
            bb = *(const bf16x8v*)((const char*)sW + colW * 256 + o);
        }
#pragma unroll
        for (int m = 0; m < 4; ++m)
            acc[m] = __builtin_amdgcn_mfma_f32_16x16x32_bf16(a[m], bb, acc[m], 0, 0, 0);
    }
}

__global__ __launch_bounds__(512, 1) void main_kernel(
    const float* __restrict__ x, const float* __restrict__ in_f,
    const float* __restrict__ Wdel1, const float* __restrict__ bdel1,
    const float* __restrict__ bdel2,
    const float* __restrict__ bgam1, const float* __restrict__ bgam2,
    const float* __restrict__ Wfc2, const float* __restrict__ bfc2,
    const float* __restrict__ base, const u16* __restrict__ psiB,
    const u16* __restrict__ alphaB, const int* __restrict__ knn,
    const u16* __restrict__ Wt, float* __restrict__ out) {
    __shared__ __align__(16) u16 sW3[3][128 * 128]; // 96 KB, resident all loop
    __shared__ __align__(16) u16 sA[64 * 128];      // 16 KB h1 -> pre -> g1
    __shared__ __align__(16) u16 sBP[64 * 128];     // 16 KB base-psi -> alpha
    __shared__ float sDiff[64][3];
    __shared__ int sIdx[64];
    __shared__ float sY[4][128];

    const int t = threadIdx.x;
    const int lane = t & 63;
    const int w = t >> 6;                            // wave 0..7
    const int kg = lane >> 4;
    const int l15 = lane & 15;
    const int colW = w * 16 + l15;                   // this thread's column

    // ---- prologue: stage 3 stage-weights (once) ----
#pragma unroll
    for (int s = 0; s < 3; ++s) {
        const u16* src = Wt + s * 16384;
        u16* dst = sW3[s];
#pragma unroll
        for (int c = 0; c < 4; ++c) {
            int lin = c * 8192 + t * 16;
            int n = lin >> 8;
            int o = lin & 255;
            bf16x8v v = *(const bf16x8v*)((const char*)src + lin);
            *(bf16x8v*)((char*)dst + n * 256 + (o ^ ((n & 7) << 4))) = v;
        }
    }
    // per-thread h1 weights: 16 fixed cols, hoisted to registers
    const int hr = t >> 3;                           // B-phase row 0..63
    const int hc0 = (t & 7) * 16;                    // B-phase col base
    float wdx[16], wdy[16], wdz[16], wdb[16];
#pragma unroll
    for (int c = 0; c < 4; ++c) {
        *(float4*)&wdx[c * 4] = *(const float4*)&Wdel1[0 * 128 + hc0 + c * 4];
        *(float4*)&wdy[c * 4] = *(const float4*)&Wdel1[1 * 128 + hc0 + c * 4];
        *(float4*)&wdz[c * 4] = *(const float4*)&Wdel1[2 * 128 + hc0 + c * 4];
        *(float4*)&wdb[c * 4] = *(const float4*)&bdel1[hc0 + c * 4];
    }
    const float bD = bdel2[colW];
    const float bG1 = bgam1[colW];
    const float bG2 = bgam2[colW];
    float bO = 0.f;
    if (t < 256) bO = bfc2[t & 63];

    const int pbase = blockIdx.x * 64;
    const int b = pbase >> 11;                       // batch (64 | 2048)

    for (int chunk = 0; chunk < 16; ++chunk) {
        const int p0 = pbase + chunk * 4;
        // ---- A: indices + diffs ----
        if (t < 64) {
            int p = p0 + (t >> 4);
            int j = knn[p * Kq + (t & 15)];
            sIdx[t] = b * Nq + j;
            const float* xq = x + (size_t)p * 3;
            const float* xn = x + (size_t)(b * Nq + j) * 3;
            sDiff[t][0] = xq[0] - xn[0];
            sDiff[t][1] = xq[1] - xn[1];
            sDiff[t][2] = xq[2] - xn[2];
        }
        __syncthreads();                             // bar0

        // ---- B: h1 -> sA, base-psi -> sBP, alpha -> regs ----
        bf16x8v aSt[2];
        {
            const float dx = sDiff[hr][0], dy = sDiff[hr][1], dz = sDiff[hr][2];
            const int nrow = sIdx[hr];
            const int prow = p0 + (hr >> 4);
            const int swz = (hr & 7) << 4;
#pragma unroll
            for (int hh = 0; hh < 2; ++hh) {
                const int c0 = hc0 + hh * 8;
                bf16x8v ps = *(const bf16x8v*)&psiB[(size_t)nrow * 128 + c0];
                float4 b0 = *(const float4*)&base[(size_t)prow * 128 + c0];
                float4 b1 = *(const float4*)&base[(size_t)prow * 128 + c0 + 4];
                aSt[hh] = *(const bf16x8v*)&alphaB[(size_t)nrow * 128 + c0];
                bf16x8v hv, bp;
#pragma unroll
                for (int j = 0; j < 8; ++j) {
                    int c = hh * 8 + j;
                    float v = fmaf(dz, wdz[c], fmaf(dy, wdy[c], fmaf(dx, wdx[c], wdb[c])));
                    hv[j] = (__bf16)fmaxf(v, 0.f);
                }
                bp[0] = (__bf16)(b0.x - (float)ps[0]); bp[1] = (__bf16)(b0.y - (float)ps[1]);
                bp[2] = (__bf16)(b0.z - (float)ps[2]); bp[3] = (__bf16)(b0.w - (float)ps[3]);
                bp[4] = (__bf16)(b1.x - (float)ps[4]); bp[5] = (__bf16)(b1.y - (float)ps[5]);
                bp[6] = (__bf16)(b1.z - (float)ps[6]); bp[7] = (__bf16)(b1.w - (float)ps[7]);
                const int ob = ((c0 * 2) ^ swz);
                *(bf16x8v*)((char*)sA + hr * 256 + ob) = hv;
                *(bf16x8v*)((char*)sBP + hr * 256 + ob) = bp;
            }
        }
        __syncthreads();                             // bar1

        // ---- del2: delta = h1 @ Wdel2 + b ----
        f32x4v accD[4];
#pragma unroll
        for (int m = 0; m < 4; ++m) accD[m] = f32x4v{bD, bD, bD, bD};
        mfma_n1(sA, sW3[0], colW, kg, l15, accD);
        __syncthreads();                             // bar2: h1 reads done

        // ---- pre = delta + bp -> sA ----
#pragma unroll
        for (int m = 0; m < 4; ++m)
#pragma unroll
            for (int rr = 0; rr < 4; ++rr) {
                int row = m * 16 + kg * 4 + rr;
                int off = row * 256 + ((colW * 2) ^ ((row & 7) << 4));
                float bpv = (float)*(const __bf16*)((const char*)sBP + off);
                *(__bf16*)((char*)sA + off) = (__bf16)(accD[m][rr] + bpv);
            }
        __syncthreads();                             // bar3: bp reads done

        // ---- alpha stash -> sBP ; gam1 ----
        {
            const int swz = (hr & 7) << 4;
            *(bf16x8v*)((char*)sBP + hr * 256 + ((hc0 * 2) ^ swz)) = aSt[0];
            *(bf16x8v*)((char*)sBP + hr * 256 + (((hc0 + 8) * 2) ^ swz)) = aSt[1];
        }
        f32x4v accT[4];
#pragma unroll
        for (int m = 0; m < 4; ++m) accT[m] = f32x4v{bG1, bG1, bG1, bG1};
        mfma_n1(sA, sW3[1], colW, kg, l15, accT);
        __syncthreads();                             // bar4: pre reads done

        // ---- g1 -> sA ----
#pragma unroll
        for (int m = 0; m < 4; ++m)
#pragma unroll
            for (int rr = 0; rr < 4; ++rr) {
                int row = m * 16 + kg * 4 + rr;
                int off = row * 256 + ((colW * 2) ^ ((row & 7) << 4));
                *(__bf16*)((char*)sA + off) = (__bf16)fmaxf(accT[m][rr], 0.f);
            }
        __syncthreads();                             // bar5

        // ---- gam2 ----
#pragma unroll
        for (int m = 0; m < 4; ++m) accT[m] = f32x4v{bG2, bG2, bG2, bG2};
        mfma_n1(sA, sW3[2], colW, kg, l15, accT);

        // ---- softmax over k + y ----
#pragma unroll
        for (int m = 0; m < 4; ++m) {
            float g0 = accT[m][0], g1v = accT[m][1], g2 = accT[m][2], g3 = accT[m][3];
            float mx = fmaxf(fmaxf(g0, g1v), fmaxf(g2, g3));
            mx = fmaxf(mx, __shfl_xor(mx, 16, 64));
            mx = fmaxf(mx, __shfl_xor(mx, 32, 64));
            float m4 = mx * 0.25f;
            float e0 = expf(0.25f * g0 - m4), e1 = expf(0.25f * g1v - m4);
            float e2 = expf(0.25f * g2 - m4), e3 = expf(0.25f * g3 - m4);
            float s = e0 + e1 + e2 + e3;
            s += __shfl_xor(s, 16, 64);
            s += __shfl_xor(s, 32, 64);
            float y = 0.f;
#pragma unroll
            for (int rr = 0; rr < 4; ++rr) {
                int row = m * 16 + kg * 4 + rr;
                int off = row * 256 + ((colW * 2) ^ ((row & 7) << 4));
                float al = (float)*(const __bf16*)((const char*)sBP + off);
                float ev = (rr == 0) ? e0 : (rr == 1) ? e1 : (rr == 2) ? e2 : e3;
                y = fmaf(ev, al + accD[m][rr], y);
            }
            y += __shfl_xor(y, 16, 64);
            y += __shfl_xor(y, 32, 64);
            if (kg == 0) sY[m][colW] = y / s;
        }
        __syncthreads();                             // bar6: sY ready, sA/sBP free

        // ---- out = y @ Wfc2 + b + in_f ----
        if (t < 256) {
            const int p = t >> 6;
            const int q = t & 63;
            const int gp = p0 + p;
            float a = bO + in_f[(size_t)gp * 64 + q];
#pragma unroll 8
            for (int d = 0; d < 128; ++d)
                a = fmaf(sY[p][d], Wfc2[d * 64 + q], a);
            out[(size_t)gp * 64 + q] = a;
        }
    }
}

// ---------------------------------------------------------------------------
extern "C" void kernel_launch(void* const* d_in, const int* in_sizes, int n_in,
                              void* d_out, int out_size, void* d_ws, size_t ws_size,
                              hipStream_t stream) {
    const float* x     = (const float*)d_in[0];
    const float* in_f  = (const float*)d_in[1];
    const float* Wfc1  = (const float*)d_in[2];
    const float* bfc1  = (const float*)d_in[3];
    const float* Wphi  = (const float*)d_in[4];
    const float* Wpsi  = (const float*)d_in[5];
    const float* Walpha= (const float*)d_in[6];
    const float* Wdpt1 = (const float*)d_in[7];
    const float* bdpt1 = (const float*)d_in[8];
    const float* Wdpt2 = (const float*)d_in[9];
    const float* bdpt2 = (const float*)d_in[10];
    const float* Wgam1 = (const float*)d_in[11];
    const float* bgam1 = (const float*)d_in[12];
    const float* Wgam2 = (const float*)d_in[13];
    const float* bgam2 = (const float*)d_in[14];
    const float* Wdel1 = (const float*)d_in[15];
    const float* bdel1 = (const float*)d_in[16];
    const float* Wdel2 = (const float*)d_in[17];
    const float* bdel2 = (const float*)d_in[18];
    const float* Wfc2  = (const float*)d_in[19];
    const float* bfc2  = (const float*)d_in[20];
    float* out = (float*)d_out;

    // ws: base f32 (8MB) | psiB bf16 (4MB) | alphaB bf16 (4MB) | knn (1MB) | Wt (272KB)
    float* base   = (float*)d_ws;
    u16*   psiB   = (u16*)(base + (size_t)BNq * Dq);
    u16*   alphaB = psiB + (size_t)BNq * Dq;
    int*   knn    = (int*)(alphaB + (size_t)BNq * Dq);
    u16*   Wt     = (u16*)(knn + (size_t)BNq * Kq);

    prep_kernel<<<WT_TOTAL / 256, 256, 0, stream>>>(Wdel2, Wgam1, Wgam2, Wfc1, Wphi,
                                                    Wpsi, Walpha, Wdpt1, Wdpt2, Wt);
    knn_kernel<<<512, 512, 0, stream>>>(x, knn);
    feat_kernel<<<BNq / 64, 256, 0, stream>>>(in_f, Wt, bfc1, bdpt1, bdpt2,
                                              base, psiB, alphaB);
    main_kernel<<<256, 512, 0, stream>>>(x, in_f, Wdel1, bdel1, bdel2,
                                         bgam1, bgam2, Wfc2, bfc2,
                                         base, psiB, alphaB, knn, Wt, out);
}

// Round 6
// 254.199 us; speedup vs baseline: 1.1409x; 1.1409x over previous
//
#include <hip/hip_runtime.h>
#include <hip/hip_bf16.h>
#include <math.h>

// Problem constants (fixed by setup_inputs)
#define Bq 8
#define Nq 2048
#define Pq 64
#define Dq 128
#define Kq 16
#define BNq (Bq * Nq)   // 16384 points total

typedef unsigned short u16;
typedef __bf16 bf16x8v __attribute__((ext_vector_type(8)));
typedef float f32x4v __attribute__((ext_vector_type(4)));

__device__ __forceinline__ u16 f2b(float f) {
    return __builtin_bit_cast(u16, (__bf16)f);      // RNE
}
__device__ __forceinline__ float b2f(u16 u) {
    return (float)__builtin_bit_cast(__bf16, u);
}

// Wt element offsets (all matrices stored transposed bf16: Wt[n][k] = W[k][n])
#define OFF_DEL2 0
#define OFF_GAM1 16384
#define OFF_GAM2 32768
#define OFF_FC1  49152
#define OFF_PHI  57344
#define OFF_PSI  73728
#define OFF_ALF  90112
#define OFF_DPT1 106496
#define OFF_DPT2 122880
#define WT_TOTAL 139264

// ---------------------------------------------------------------------------
// Kernel 0: transpose+convert all 9 matmul weights -> bf16 Wt[n][K] linear.
// ---------------------------------------------------------------------------
__global__ __launch_bounds__(256) void prep_kernel(
    const float* __restrict__ Wdel2, const float* __restrict__ Wgam1,
    const float* __restrict__ Wgam2, const float* __restrict__ Wfc1,
    const float* __restrict__ Wphi, const float* __restrict__ Wpsi,
    const float* __restrict__ Walpha, const float* __restrict__ Wdpt1,
    const float* __restrict__ Wdpt2, u16* __restrict__ Wt) {
    int idx = blockIdx.x * 256 + threadIdx.x;       // 0..139263
    const float* W;
    int n, k;
    if (idx < OFF_FC1) {
        int m = idx >> 14, r = idx & 16383;
        W = (m == 0) ? Wdel2 : (m == 1) ? Wgam1 : Wgam2;
        n = r >> 7; k = r & 127;
    } else if (idx < OFF_PHI) {
        int r = idx - OFF_FC1;
        W = Wfc1; n = r >> 6; k = r & 63;
    } else {
        int r = idx - OFF_PHI;
        int m = r >> 14; r &= 16383;
        W = (m == 0) ? Wphi : (m == 1) ? Wpsi : (m == 2) ? Walpha : (m == 3) ? Wdpt1 : Wdpt2;
        n = r >> 7; k = r & 127;
    }
    Wt[idx] = f2b(W[k * 128 + n]);
}

// ---------------------------------------------------------------------------
// Kernel 1 (v2, reverted): exact kNN. 512 blocks x 256 threads.
// Block = 32 queries x 8 candidate-chunks of 256; per-thread top-16 insertion
// then stable lexicographic 8-way merge. Measured-good in rounds 2-3.
// ---------------------------------------------------------------------------
__global__ __launch_bounds__(256) void knn_kernel(const float* __restrict__ x,
                                                  int* __restrict__ knn) {
    __shared__ float4 sx[Nq];                       // 32 KB
    __shared__ float sLd[32][8][17];
    __shared__ int   sLi[32][8][17];
    const int b = blockIdx.x >> 6;
    const int q0 = (blockIdx.x & 63) * 32;
    const float* xb = x + b * Nq * 3;
    for (int j = threadIdx.x; j < Nq; j += 256) {
        float x0 = xb[j * 3 + 0], x1 = xb[j * 3 + 1], x2 = xb[j * 3 + 2];
        // replicate jnp.sum(x*x): no fma contraction
        float n2 = __fadd_rn(__fadd_rn(__fmul_rn(x0, x0), __fmul_rn(x1, x1)),
                             __fmul_rn(x2, x2));
        sx[j] = make_float4(x0, x1, x2, n2);
    }
    __syncthreads();
    const int q = threadIdx.x & 31;
    const int sub = threadIdx.x >> 5;
    const float4 qv = sx[q0 + q];
    float bd[Kq];
    int bj[Kq];
#pragma unroll
    for (int s = 0; s < Kq; ++s) { bd[s] = INFINITY; bj[s] = 0; }
    const int j0 = sub * 256;
    for (int i = 0; i < 256; ++i) {
        const int j = j0 + i;
        float4 p = sx[j];
        float dot = __fadd_rn(__fadd_rn(__fmul_rn(qv.x, p.x), __fmul_rn(qv.y, p.y)),
                              __fmul_rn(qv.z, p.z));
        float d = __fsub_rn(__fadd_rn(qv.w, p.w), __fmul_rn(2.0f, dot));
        if (d < bd[Kq - 1]) {                       // strict <: stable
            bd[Kq - 1] = d; bj[Kq - 1] = j;
#pragma unroll
            for (int s = Kq - 1; s >= 1; --s) {
                if (bd[s] < bd[s - 1]) {
                    float td = bd[s]; bd[s] = bd[s - 1]; bd[s - 1] = td;
                    int tj = bj[s]; bj[s] = bj[s - 1]; bj[s - 1] = tj;
                }
            }
        }
    }
#pragma unroll
    for (int s = 0; s < Kq; ++s) { sLd[q][sub][s] = bd[s]; sLi[q][sub][s] = bj[s]; }
    __syncthreads();
    if (threadIdx.x < 32) {
        const int mq = threadIdx.x;
        int pos[8]; float hd[8]; int hi[8];
#pragma unroll
        for (int s = 0; s < 8; ++s) {
            pos[s] = 1; hd[s] = sLd[mq][s][0]; hi[s] = sLi[mq][s][0];
        }
        int* o = knn + (b * Nq + q0 + mq) * Kq;
#pragma unroll
        for (int oi = 0; oi < Kq; ++oi) {
            float bdv = hd[0]; int biv = hi[0]; int bs = 0;
#pragma unroll
            for (int s = 1; s < 8; ++s) {
                bool take = (hd[s] < bdv) || (hd[s] == bdv && hi[s] < biv);
                if (take) { bdv = hd[s]; biv = hi[s]; bs = s; }
            }
            o[oi] = biv;
#pragma unroll
            for (int s = 0; s < 8; ++s) {           // static-index update
                if (s == bs) {
                    int pp = pos[s] < Kq ? pos[s] : (Kq - 1);
                    bool ok = pos[s] < Kq;
                    hd[s] = ok ? sLd[mq][s][pp] : INFINITY;
                    hi[s] = ok ? sLi[mq][s][pp] : 0x7fffffff;
                    pos[s]++;
                }
            }
        }
    }
}

// ---------------------------------------------------------------------------
// Shared MFMA helpers (feat kernel). XOR swizzle byte ^= (row&7)<<4.
// ---------------------------------------------------------------------------
template <int BYTES, int ROWBYTES>
__device__ __forceinline__ void stageW(const u16* __restrict__ src,
                                       u16* __restrict__ sW, int t) {
#pragma unroll
    for (int c = 0; c < BYTES / 4096; ++c) {
        int lin = c * 4096 + t * 16;
        int n = lin / ROWBYTES;
        int o = lin % ROWBYTES;
        bf16x8v v = *(const bf16x8v*)((const char*)src + lin);
        *(bf16x8v*)((char*)sW + n * ROWBYTES + (o ^ ((n & 7) << 4))) = v;
    }
}

__device__ __forceinline__ void mfma_k128(const u16* __restrict__ sA,
                                          const u16* __restrict__ sW,
                                          int colbase, int lane,
                                          f32x4v (&acc)[4][2]) {
    const int kg = lane >> 4;
    const int l15 = lane & 15;
#pragma unroll
    for (int ks = 0; ks < 4; ++ks) {
        bf16x8v a[4], bfr[2];
#pragma unroll
        for (int m = 0; m < 4; ++m) {
            int row = m * 16 + l15;
            int o = (ks * 64 + kg * 16) ^ ((row & 7) << 4);
            a[m] = *(const bf16x8v*)((const char*)sA + row * 256 + o);
        }
#pragma unroll
        for (int nt = 0; nt < 2; ++nt) {
            int n = colbase + nt * 16 + l15;
            int o = (ks * 64 + kg * 16) ^ ((n & 7) << 4);
            bfr[nt] = *(const bf16x8v*)((const char*)sW + n * 256 + o);
        }
#pragma unroll
        for (int m = 0; m < 4; ++m)
#pragma unroll
            for (int nt = 0; nt < 2; ++nt)
                acc[m][nt] = __builtin_amdgcn_mfma_f32_16x16x32_bf16(a[m], bfr[nt], acc[m][nt], 0, 0, 0);
    }
}

__device__ __forceinline__ void mfma_k64(const u16* __restrict__ sA,
                                         const u16* __restrict__ sW,
                                         int colbase, int lane,
                                         f32x4v (&acc)[4][2]) {
    const int kg = lane >> 4;
    const int l15 = lane & 15;
#pragma unroll
    for (int ks = 0; ks < 2; ++ks) {
        bf16x8v a[4], bfr[2];
#pragma unroll
        for (int m = 0; m < 4; ++m) {
            int row = m * 16 + l15;
            int o = (ks * 64 + kg * 16) ^ ((row & 7) << 4);
            a[m] = *(const bf16x8v*)((const char*)sA + row * 128 + o);
        }
#pragma unroll
        for (int nt = 0; nt < 2; ++nt) {
            int n = colbase + nt * 16 + l15;
            int o = (ks * 64 + kg * 16) ^ ((n & 7) << 4);
            bfr[nt] = *(const bf16x8v*)((const char*)sW + n * 128 + o);
        }
#pragma unroll
        for (int m = 0; m < 4; ++m)
#pragma unroll
            for (int nt = 0; nt < 2; ++nt)
                acc[m][nt] = __builtin_amdgcn_mfma_f32_16x16x32_bf16(a[m], bfr[nt], acc[m][nt], 0, 0, 0);
    }
}

// ---------------------------------------------------------------------------
// Kernel 2 (MFMA): per-point features, 64 points/block, 256 blocks x 4 waves.
// (unchanged from round 3)
// ---------------------------------------------------------------------------
__global__ __launch_bounds__(256, 2) void feat_kernel(
    const float* __restrict__ in_f, const u16* __restrict__ Wt,
    const float* __restrict__ bfc1, const float* __restrict__ bdpt1,
    const float* __restrict__ bdpt2,
    float* __restrict__ base, u16* __restrict__ psiB, u16* __restrict__ alphaB) {
    __shared__ __align__(16) u16 sIn[64 * 64];      // 8 KB
    __shared__ __align__(16) u16 sF[64 * 128];      // 16 KB
    __shared__ __align__(16) u16 sW[128 * 128];     // 32 KB
    const int t = threadIdx.x;
    const int lane = t & 63;
    const int w = t >> 6;
    const int kg = lane >> 4;
    const int l15 = lane & 15;
    const int p0 = blockIdx.x * 64;

    {
        const int r = t >> 2;
        const int c0 = (t & 3) * 16;
        const float* src = &in_f[(size_t)(p0 + r) * 64 + c0];
        float4 v0 = *(const float4*)(src + 0);
        float4 v1 = *(const float4*)(src + 4);
        float4 v2 = *(const float4*)(src + 8);
        float4 v3 = *(const float4*)(src + 12);
        bf16x8v lo, hi;
        lo[0] = (__bf16)v0.x; lo[1] = (__bf16)v0.y; lo[2] = (__bf16)v0.z; lo[3] = (__bf16)v0.w;
        lo[4] = (__bf16)v1.x; lo[5] = (__bf16)v1.y; lo[6] = (__bf16)v1.z; lo[7] = (__bf16)v1.w;
        hi[0] = (__bf16)v2.x; hi[1] = (__bf16)v2.y; hi[2] = (__bf16)v2.z; hi[3] = (__bf16)v2.w;
        hi[4] = (__bf16)v3.x; hi[5] = (__bf16)v3.y; hi[6] = (__bf16)v3.z; hi[7] = (__bf16)v3.w;
        const int swz = (r & 7) << 4;
        *(bf16x8v*)((char*)sIn + r * 128 + ((c0 * 2) ^ swz)) = lo;
        *(bf16x8v*)((char*)sIn + r * 128 + (((c0 + 8) * 2) ^ swz)) = hi;
    }

    f32x4v acc[4][2], accPhi[4][2];

    {
        float bv0 = bfc1[w * 32 + l15];
        float bv1 = bfc1[w * 32 + 16 + l15];
#pragma unroll
        for (int m = 0; m < 4; ++m) { acc[m][0] = f32x4v{bv0, bv0, bv0, bv0}; acc[m][1] = f32x4v{bv1, bv1, bv1, bv1}; }
    }
    stageW<16384, 128>(Wt + OFF_FC1, sW, t);
    __syncthreads();
    mfma_k64(sIn, sW, w * 32, lane, acc);

#pragma unroll
    for (int m = 0; m < 4; ++m)
#pragma unroll
        for (int nt = 0; nt < 2; ++nt)
#pragma unroll
            for (int rr = 0; rr < 4; ++rr) {
                int row = m * 16 + kg * 4 + rr;
                int col = w * 32 + nt * 16 + l15;
                *(__bf16*)((char*)sF + row * 256 + ((col * 2) ^ ((row & 7) << 4))) = (__bf16)acc[m][nt][rr];
            }

#pragma unroll
    for (int m = 0; m < 4; ++m) { accPhi[m][0] = f32x4v{0, 0, 0, 0}; accPhi[m][1] = f32x4v{0, 0, 0, 0}; }
    __syncthreads();
    stageW<32768, 256>(Wt + OFF_PHI, sW, t);
    __syncthreads();
    mfma_k128(sF, sW, w * 32, lane, accPhi);

#pragma unroll
    for (int m = 0; m < 4; ++m) { acc[m][0] = f32x4v{0, 0, 0, 0}; acc[m][1] = f32x4v{0, 0, 0, 0}; }
    __syncthreads();
    stageW<32768, 256>(Wt + OFF_PSI, sW, t);
    __syncthreads();
    mfma_k128(sF, sW, w * 32, lane, acc);
#pragma unroll
    for (int m = 0; m < 4; ++m)
#pragma unroll
        for (int nt = 0; nt < 2; ++nt)
#pragma unroll
            for (int rr = 0; rr < 4; ++rr) {
                int row = m * 16 + kg * 4 + rr;
                int col = w * 32 + nt * 16 + l15;
                psiB[(size_t)(p0 + row) * 128 + col] = f2b(acc[m][nt][rr]);
            }

#pragma unroll
    for (int m = 0; m < 4; ++m) { acc[m][0] = f32x4v{0, 0, 0, 0}; acc[m][1] = f32x4v{0, 0, 0, 0}; }
    __syncthreads();
    stageW<32768, 256>(Wt + OFF_ALF, sW, t);
    __syncthreads();
    mfma_k128(sF, sW, w * 32, lane, acc);
#pragma unroll
    for (int m = 0; m < 4; ++m)
#pragma unroll
        for (int nt = 0; nt < 2; ++nt)
#pragma unroll
            for (int rr = 0; rr < 4; ++rr) {
                int row = m * 16 + kg * 4 + rr;
                int col = w * 32 + nt * 16 + l15;
                alphaB[(size_t)(p0 + row) * 128 + col] = f2b(acc[m][nt][rr]);
            }

    {
        float bv0 = bdpt1[w * 32 + l15];
        float bv1 = bdpt1[w * 32 + 16 + l15];
#pragma unroll
        for (int m = 0; m < 4; ++m) { acc[m][0] = f32x4v{bv0, bv0, bv0, bv0}; acc[m][1] = f32x4v{bv1, bv1, bv1, bv1}; }
    }
    __syncthreads();
    stageW<32768, 256>(Wt + OFF_DPT1, sW, t);
    __syncthreads();
    mfma_k128(sF, sW, w * 32, lane, acc);
    __syncthreads();
#pragma unroll
    for (int m = 0; m < 4; ++m)
#pragma unroll
        for (int nt = 0; nt < 2; ++nt)
#pragma unroll
            for (int rr = 0; rr < 4; ++rr) {
                int row = m * 16 + kg * 4 + rr;
                int col = w * 32 + nt * 16 + l15;
                *(__bf16*)((char*)sF + row * 256 + ((col * 2) ^ ((row & 7) << 4))) =
                    (__bf16)fmaxf(acc[m][nt][rr], 0.f);
            }

    {
        float bv0 = bdpt2[w * 32 + l15];
        float bv1 = bdpt2[w * 32 + 16 + l15];
#pragma unroll
        for (int m = 0; m < 4; ++m) { acc[m][0] = f32x4v{bv0, bv0, bv0, bv0}; acc[m][1] = f32x4v{bv1, bv1, bv1, bv1}; }
    }
    __syncthreads();
    stageW<32768, 256>(Wt + OFF_DPT2, sW, t);
    __syncthreads();
    mfma_k128(sF, sW, w * 32, lane, acc);
#pragma unroll
    for (int m = 0; m < 4; ++m)
#pragma unroll
        for (int nt = 0; nt < 2; ++nt)
#pragma unroll
            for (int rr = 0; rr < 4; ++rr) {
                int row = m * 16 + kg * 4 + rr;
                int col = w * 32 + nt * 16 + l15;
                base[(size_t)(p0 + row) * 128 + col] = acc[m][nt][rr] + accPhi[m][nt][rr];
            }
}

// ---------------------------------------------------------------------------
// Kernel 3 (v4): 1024 blocks x 512 threads (8 waves), 4 chunks x 4 points.
// gam1/gam2 weights in REGISTERS (32 VGPR/lane); del2 weights in LDS staged
// once per block. bp/alpha gathered from global (no sBP). 6 barriers/chunk.
// LDS ~51 KB, target 2 blocks/CU (16 waves).
// ---------------------------------------------------------------------------
__device__ __forceinline__ void mfma_ldsB(const u16* __restrict__ sA,
                                          const u16* __restrict__ sW,
                                          int colW, int kg, int l15,
                                          f32x4v (&acc)[4]) {
#pragma unroll
    for (int ks = 0; ks < 4; ++ks) {
        bf16x8v a[4], bb;
#pragma unroll
        for (int m = 0; m < 4; ++m) {
            int row = m * 16 + l15;
            int o = (ks * 64 + kg * 16) ^ ((row & 7) << 4);
            a[m] = *(const bf16x8v*)((const char*)sA + row * 256 + o);
        }
        {
            int o = (ks * 64 + kg * 16) ^ ((colW & 7) << 4);
            bb = *(const bf16x8v*)((const char*)sW + colW * 256 + o);
        }
#pragma unroll
        for (int m = 0; m < 4; ++m)
            acc[m] = __builtin_amdgcn_mfma_f32_16x16x32_bf16(a[m], bb, acc[m], 0, 0, 0);
    }
}

__device__ __forceinline__ void mfma_regB(const u16* __restrict__ sA,
                                          const bf16x8v (&wB)[4],
                                          int kg, int l15,
                                          f32x4v (&acc)[4]) {
#pragma unroll
    for (int ks = 0; ks < 4; ++ks) {
#pragma unroll
        for (int m = 0; m < 4; ++m) {
            int row = m * 16 + l15;
            int o = (ks * 64 + kg * 16) ^ ((row & 7) << 4);
            bf16x8v a = *(const bf16x8v*)((const char*)sA + row * 256 + o);
            acc[m] = __builtin_amdgcn_mfma_f32_16x16x32_bf16(a, wB[ks], acc[m], 0, 0, 0);
        }
    }
}

__global__ __launch_bounds__(512, 4) void main_kernel(
    const float* __restrict__ x, const float* __restrict__ in_f,
    const float* __restrict__ Wdel1, const float* __restrict__ bdel1,
    const float* __restrict__ bdel2,
    const float* __restrict__ bgam1, const float* __restrict__ bgam2,
    const float* __restrict__ Wfc2, const float* __restrict__ bfc2,
    const float* __restrict__ base, const u16* __restrict__ psiB,
    const u16* __restrict__ alphaB, const int* __restrict__ knn,
    const u16* __restrict__ Wt, float* __restrict__ out) {
    __shared__ __align__(16) u16 sWd2[128 * 128];   // 32 KB del2 weights (swz)
    __shared__ __align__(16) u16 sA[64 * 128];      // 16 KB h1 -> pre -> g1 (swz)
    __shared__ float sWd1[512];                     // Wdel1 rows + bias at 384
    __shared__ int sIdx[64];
    __shared__ float sY[4][128];

    const int t = threadIdx.x;
    const int lane = t & 63;
    const int w = t >> 6;                            // wave 0..7
    const int kg = lane >> 4;
    const int l15 = lane & 15;
    const int colW = w * 16 + l15;                   // this thread's out column

    // ---- prologue ----
    // del2 weights -> LDS (once)
#pragma unroll
    for (int c = 0; c < 4; ++c) {
        int lin = c * 8192 + t * 16;
        int n = lin >> 8;
        int o = lin & 255;
        bf16x8v v = *(const bf16x8v*)((const char*)(Wt + OFF_DEL2) + lin);
        *(bf16x8v*)((char*)sWd2 + n * 256 + (o ^ ((n & 7) << 4))) = v;
    }
    // Wdel1 + bias -> LDS
    {
        int idx = t;
        if (idx < 512) sWd1[idx] = (idx < 384) ? Wdel1[idx] : bdel1[idx - 384];
    }
    // gam1/gam2 B-fragments -> registers (per-lane, coalesced 16B)
    bf16x8v wG1[4], wG2[4];
#pragma unroll
    for (int ks = 0; ks < 4; ++ks) {
        size_t off = (size_t)colW * 128 + ks * 32 + kg * 8;
        wG1[ks] = *(const bf16x8v*)(Wt + OFF_GAM1 + off);
        wG2[ks] = *(const bf16x8v*)(Wt + OFF_GAM2 + off);
    }
    const float bD = bdel2[colW];
    const float bG1 = bgam1[colW];
    const float bG2 = bgam2[colW];
    float bO = 0.f;
    if (t < 256) bO = bfc2[t & 63];

    const int pbase = blockIdx.x * 16;               // 16 points per block
    const int b = pbase >> 11;
    const int hr = t >> 3;                           // B-phase row 0..63
    const int hc0 = (t & 7) * 16;                    // B-phase col base

    for (int chunk = 0; chunk < 4; ++chunk) {
        const int p0 = pbase + chunk * 4;

        // ---- A (t<64): neighbor indices -> LDS ----
        if (t < 64) {
            int p = p0 + (t >> 4);
            sIdx[t] = b * Nq + knn[p * Kq + (t & 15)];
        }

        // ---- B: h1 = relu(diff @ Wdel1 + b) -> sA (inline diff, no sDiff) ----
        {
            const int p = p0 + (hr >> 4);
            const int j = knn[p * Kq + (hr & 15)];
            const float* xq = x + (size_t)p * 3;
            const float* xn = x + (size_t)(b * Nq + j) * 3;
            const float dx = xq[0] - xn[0];
            const float dy = xq[1] - xn[1];
            const float dz = xq[2] - xn[2];
            const int swzB = (hr & 7) << 4;
#pragma unroll
            for (int hh = 0; hh < 2; ++hh) {
                bf16x8v hv;
#pragma unroll
                for (int c4 = 0; c4 < 2; ++c4) {
                    const int cc = hc0 + hh * 8 + c4 * 4;
                    float4 wx = *(const float4*)&sWd1[cc];
                    float4 wy = *(const float4*)&sWd1[128 + cc];
                    float4 wz = *(const float4*)&sWd1[256 + cc];
                    float4 b4 = *(const float4*)&sWd1[384 + cc];
                    hv[c4 * 4 + 0] = (__bf16)fmaxf(fmaf(dz, wz.x, fmaf(dy, wy.x, fmaf(dx, wx.x, b4.x))), 0.f);
                    hv[c4 * 4 + 1] = (__bf16)fmaxf(fmaf(dz, wz.y, fmaf(dy, wy.y, fmaf(dx, wx.y, b4.y))), 0.f);
                    hv[c4 * 4 + 2] = (__bf16)fmaxf(fmaf(dz, wz.z, fmaf(dy, wy.z, fmaf(dx, wx.z, b4.z))), 0.f);
                    hv[c4 * 4 + 3] = (__bf16)fmaxf(fmaf(dz, wz.w, fmaf(dy, wy.w, fmaf(dx, wx.w, b4.w))), 0.f);
                }
                *(bf16x8v*)((char*)sA + hr * 256 + (((hc0 + hh * 8) * 2) ^ swzB)) = hv;
            }
        }
        __syncthreads();                             // bar1: h1+sIdx ready (also sWd2 on chunk 0)

        // ---- del2: delta = h1 @ Wdel2 + b ----
        f32x4v accD[4];
#pragma unroll
        for (int m = 0; m < 4; ++m) accD[m] = f32x4v{bD, bD, bD, bD};
        mfma_ldsB(sA, sWd2, colW, kg, l15, accD);
        __syncthreads();                             // bar2: h1 reads done

        // ---- pre = delta + (base - psi) -> sA (bp straight from global) ----
#pragma unroll
        for (int m = 0; m < 4; ++m) {
            const float bs = base[(size_t)(p0 + m) * 128 + colW];
#pragma unroll
            for (int rr = 0; rr < 4; ++rr) {
                int row = m * 16 + kg * 4 + rr;
                float ps = b2f(psiB[(size_t)sIdx[row] * 128 + colW]);
                int off = row * 256 + ((colW * 2) ^ ((row & 7) << 4));
                *(__bf16*)((char*)sA + off) = (__bf16)(accD[m][rr] + (bs - ps));
            }
        }
        __syncthreads();                             // bar3: pre ready

        // ---- gam1 (reg weights): g1 = relu(pre @ Wgam1 + b) ----
        f32x4v accT[4];
#pragma unroll
        for (int m = 0; m < 4; ++m) accT[m] = f32x4v{bG1, bG1, bG1, bG1};
        mfma_regB(sA, wG1, kg, l15, accT);
        __syncthreads();                             // bar4: pre reads done

        // ---- g1 -> sA ----
#pragma unroll
        for (int m = 0; m < 4; ++m)
#pragma unroll
            for (int rr = 0; rr < 4; ++rr) {
                int row = m * 16 + kg * 4 + rr;
                int off = row * 256 + ((colW * 2) ^ ((row & 7) << 4));
                *(__bf16*)((char*)sA + off) = (__bf16)fmaxf(accT[m][rr], 0.f);
            }
        __syncthreads();                             // bar5: g1 ready

        // ---- gam2 (reg weights) ----
#pragma unroll
        for (int m = 0; m < 4; ++m) accT[m] = f32x4v{bG2, bG2, bG2, bG2};
        mfma_regB(sA, wG2, kg, l15, accT);

        // ---- softmax over k + y (alpha straight from global) ----
#pragma unroll
        for (int m = 0; m < 4; ++m) {
            float g0 = accT[m][0], g1v = accT[m][1], g2 = accT[m][2], g3 = accT[m][3];
            float mx = fmaxf(fmaxf(g0, g1v), fmaxf(g2, g3));
            mx = fmaxf(mx, __shfl_xor(mx, 16, 64));
            mx = fmaxf(mx, __shfl_xor(mx, 32, 64));
            float m4 = mx * 0.25f;
            float e0 = expf(0.25f * g0 - m4), e1 = expf(0.25f * g1v - m4);
            float e2 = expf(0.25f * g2 - m4), e3 = expf(0.25f * g3 - m4);
            float s = e0 + e1 + e2 + e3;
            s += __shfl_xor(s, 16, 64);
            s += __shfl_xor(s, 32, 64);
            float y = 0.f;
#pragma unroll
            for (int rr = 0; rr < 4; ++rr) {
                int row = m * 16 + kg * 4 + rr;
                float al = b2f(alphaB[(size_t)sIdx[row] * 128 + colW]);
                float ev = (rr == 0) ? e0 : (rr == 1) ? e1 : (rr == 2) ? e2 : e3;
                y = fmaf(ev, al + accD[m][rr], y);
            }
            y += __shfl_xor(y, 16, 64);
            y += __shfl_xor(y, 32, 64);
            if (kg == 0) sY[m][colW] = y / s;
        }
        __syncthreads();                             // bar6: sY ready; sA/sIdx free

        // ---- out = y @ Wfc2 + b + in_f (waves 0-3; others run ahead to B') ----
        if (t < 256) {
            const int p = t >> 6;
            const int q = t & 63;
            const int gp = p0 + p;
            float a = bO + in_f[(size_t)gp * 64 + q];
#pragma unroll 8
            for (int d = 0; d < 128; ++d)
                a = fmaf(sY[p][d], Wfc2[d * 64 + q], a);
            out[(size_t)gp * 64 + q] = a;
        }
    }
}

// ---------------------------------------------------------------------------
extern "C" void kernel_launch(void* const* d_in, const int* in_sizes, int n_in,
                              void* d_out, int out_size, void* d_ws, size_t ws_size,
                              hipStream_t stream) {
    const float* x     = (const float*)d_in[0];
    const float* in_f  = (const float*)d_in[1];
    const float* Wfc1  = (const float*)d_in[2];
    const float* bfc1  = (const float*)d_in[3];
    const float* Wphi  = (const float*)d_in[4];
    const float* Wpsi  = (const float*)d_in[5];
    const float* Walpha= (const float*)d_in[6];
    const float* Wdpt1 = (const float*)d_in[7];
    const float* bdpt1 = (const float*)d_in[8];
    const float* Wdpt2 = (const float*)d_in[9];
    const float* bdpt2 = (const float*)d_in[10];
    const float* Wgam1 = (const float*)d_in[11];
    const float* bgam1 = (const float*)d_in[12];
    const float* Wgam2 = (const float*)d_in[13];
    const float* bgam2 = (const float*)d_in[14];
    const float* Wdel1 = (const float*)d_in[15];
    const float* bdel1 = (const float*)d_in[16];
    const float* Wdel2 = (const float*)d_in[17];
    const float* bdel2 = (const float*)d_in[18];
    const float* Wfc2  = (const float*)d_in[19];
    const float* bfc2  = (const float*)d_in[20];
    float* out = (float*)d_out;

    // ws: base f32 (8MB) | psiB bf16 (4MB) | alphaB bf16 (4MB) | knn (1MB) | Wt (272KB)
    float* base   = (float*)d_ws;
    u16*   psiB   = (u16*)(base + (size_t)BNq * Dq);
    u16*   alphaB = psiB + (size_t)BNq * Dq;
    int*   knn    = (int*)(alphaB + (size_t)BNq * Dq);
    u16*   Wt     = (u16*)(knn + (size_t)BNq * Kq);

    prep_kernel<<<WT_TOTAL / 256, 256, 0, stream>>>(Wdel2, Wgam1, Wgam2, Wfc1, Wphi,
                                                    Wpsi, Walpha, Wdpt1, Wdpt2, Wt);
    knn_kernel<<<512, 256, 0, stream>>>(x, knn);
    feat_kernel<<<BNq / 64, 256, 0, stream>>>(in_f, Wt, bfc1, bdpt1, bdpt2,
                                              base, psiB, alphaB);
    main_kernel<<<BNq / 16, 512, 0, stream>>>(x, in_f, Wdel1, bdel1, bdel2,
                                              bgam1, bgam2, Wfc2, bfc2,
                                              base, psiB, alphaB, knn, Wt, out);
}